// Round 2
// baseline (867.060 us; speedup 1.0000x reference)
//
#include <hip/hip_runtime.h>
#include <stdint.h>

// ---------------------------------------------------------------------------
// 21 hand-graph nodes, each a 3-layer MLP over B=65536 rows:
//   h1 = relu(concat(x[neighbors]) @ w1 + b1)   [K = n*64 -> 128]
//   h2 = relu(h1 @ w2 + b2)                     [128 -> 128]
//   out[:, out_joint] = h2 @ w3 + b3            [128 -> 64]
// Strategy: bf16 MFMA (16x16x32), feature-major (M=features, N=batch).
//   - prepass converts+transposes weights into d_ws as bf16 images [f][72]
//   - main kernel: 1 block = (node, 128 batch rows), 4 waves in 2x2 tile grid
//   - activations live in LDS row-major [batch][k] (natural B-fragment feed)
//   - epilogues write h as packed 4-bf16 ds_write_b64 (C/D rows are contiguous)
// R2 fix: prepass grid was 8 wide; layer-3 chunks for n=5/n=6 nodes live at
//   c8=8,9 and were never generated (joints 0,5,9,13 read 0xAA poison). ->10.
// ---------------------------------------------------------------------------

#define CH   18432   // bytes of one [128][72] bf16 weight chunk image
#define CH3  9216    // bytes of one [64][72] bf16 w3 chunk image
#define WSNEED 2459904u

typedef __attribute__((ext_vector_type(8))) short bf16x8;
typedef __attribute__((ext_vector_type(4))) float f32x4;

static __device__ __forceinline__ ushort f2bf(float f) {
  union { float f; uint32_t u; } v; v.f = f;
  return (ushort)((v.u + 0x7FFFu + ((v.u >> 16) & 1u)) >> 16);  // RNE
}

__device__ const int g_n[21]   = {6,5,5,5,4,4,3,3,3,3,3,3,3,3,3,3,2,2,2,2,2};
__device__ const int g_out[21] = {0,5,9,13,1,17,2,3,6,7,10,11,14,15,18,19,4,8,12,16,20};
__device__ const int g_gi[21]  = {0,1,1,1,2,2,3,3,3,3,3,3,3,3,3,3,4,4,4,4,4};
__device__ const int g_ki[21]  = {0,0,1,2,0,1,0,1,2,3,4,5,6,7,8,9,0,1,2,3,4};
__device__ const int g_neigh[21][6] = {
  {0,1,5,9,13,17},
  {0,5,6,1,9},{0,9,10,5,13},{0,13,14,9,17},
  {0,1,2,5},{0,17,18,13},
  {1,2,3},{2,3,4},{5,6,7},{6,7,8},{9,10,11},{10,11,12},
  {13,14,15},{14,15,16},{17,18,19},{18,19,20},
  {3,4},{7,8},{11,12},{15,16},{19,20}};
__device__ const uint32_t g_wsoff[21] = {
  0,167168,315904,464640,613376,743680,873984,985856,1097728,1209600,
  1321472,1433344,1545216,1657088,1768960,1880832,1992704,2086144,
  2179584,2273024,2366464};

struct WPtrs {
  const float* w1[5]; const float* b1[5];
  const float* w2[5]; const float* b2[5];
  const float* w3[5]; const float* b3[5];
};

// ---------------- prepass: fp32 weights -> transposed bf16 images in ws ----
__global__ void prep_weights(WPtrs p, ushort* ws) {
  const int node = blockIdx.y, c8 = blockIdx.x, tid = threadIdx.x;
  const int n = g_n[node], gi = g_gi[node], ki = g_ki[node];
  char* base = (char*)ws + g_wsoff[node];

  if (c8 < n) {                       // layer-1 chunk c8: w1[ki][c8*64+kk][f]
    const float* src = p.w1[gi] + ((size_t)(ki * n + c8) * 64) * 128;
    ushort* dst = (ushort*)(base + (size_t)c8 * CH);
    for (int pos = tid; pos < 128 * 72; pos += 256) {
      int f = pos & 127, kk = pos >> 7;
      float v = (kk < 64) ? src[kk * 128 + f] : 0.f;
      dst[f * 72 + kk] = f2bf(v);
    }
  } else if (c8 < n + 2) {            // layer-2 chunk
    int c = c8 - n;
    const float* src = p.w2[gi] + ((size_t)ki * 128 + c * 64) * 128;
    ushort* dst = (ushort*)(base + (size_t)(n + c) * CH);
    for (int pos = tid; pos < 128 * 72; pos += 256) {
      int f = pos & 127, kk = pos >> 7;
      float v = (kk < 64) ? src[kk * 128 + f] : 0.f;
      dst[f * 72 + kk] = f2bf(v);
    }
  } else if (c8 < n + 4) {            // layer-3 chunk ([64 f][72])
    int c = c8 - n - 2;
    const float* src = p.w3[gi] + ((size_t)ki * 128 + c * 64) * 64;
    ushort* dst = (ushort*)(base + (size_t)(n + 2) * CH + (size_t)c * CH3);
    for (int pos = tid; pos < 64 * 72; pos += 256) {
      int f = pos & 63, kk = pos >> 6;
      float v = (kk < 64) ? src[kk * 64 + f] : 0.f;
      dst[f * 72 + kk] = f2bf(v);
    }
  }
  if (c8 == 0) {                      // biases (fp32) after all chunks
    float* bdst = (float*)(base + (size_t)(n + 3) * CH);
    for (int t = tid; t < 320; t += 256) {
      float v;
      if (t < 128)       v = p.b1[gi][ki * 128 + t];
      else if (t < 256)  v = p.b2[gi][ki * 128 + (t - 128)];
      else               v = p.b3[gi][ki * 64 + (t - 256)];
      bdst[t] = v;
    }
  }
}

// ---------------- main MFMA kernel -----------------------------------------
__global__ __launch_bounds__(256, 2)
void mp_mlp(const float* __restrict__ x, float* __restrict__ out,
            const ushort* __restrict__ ws) {
  // LDS: sH [128 batch][136] bf16 (h buffer; first [128][72] aliased as x-stage)
  //      sW [128][72] bf16 weight chunk
  __shared__ ushort sH[128 * 136];   // 34816 B
  __shared__ ushort sW[128 * 72];    // 18432 B   (total 52 KB -> 3 blocks/CU)

  const int node = blockIdx.x % 21;
  const int tile = blockIdx.x / 21;
  const int b0 = tile * 128;
  const int tid = threadIdx.x;
  const int lane = tid & 63, w = tid >> 6;
  const int quad = lane >> 4, l16 = lane & 15;
  const int wr = w >> 1, wc = w & 1;          // 2x2 wave grid (f-half, batch-half)
  const int n = g_n[node];
  const char* wsbase = (const char*)ws + g_wsoff[node];
  const float* bias = (const float*)(wsbase + (size_t)(n + 3) * CH);

  f32x4 acc[4][4];
  #pragma unroll
  for (int a = 0; a < 4; ++a)
    #pragma unroll
    for (int b = 0; b < 4; ++b) acc[a][b] = (f32x4){0.f, 0.f, 0.f, 0.f};

  // ---------------- layer 1: K = n*64, chunked per neighbor ----------------
  for (int s = 0; s < n; ++s) {
    if (s) __syncthreads();
    // stage x[b0..b0+127][neigh][0..63] -> bf16 into sH-as-x (stride 72)
    {
      const int nb = g_neigh[node][s];
      const float* xsrc = x + (size_t)b0 * 1344 + nb * 64;
      #pragma unroll
      for (int i = 0; i < 8; ++i) {
        int c = tid + (i << 8);            // float4 id, 2048 total
        int r = c >> 4, dc = (c & 15) << 2;
        float4 v = *reinterpret_cast<const float4*>(xsrc + (size_t)r * 1344 + dc);
        ushort4 u;
        u.x = f2bf(v.x); u.y = f2bf(v.y); u.z = f2bf(v.z); u.w = f2bf(v.w);
        *reinterpret_cast<ushort4*>(&sH[r * 72 + dc]) = u;
      }
    }
    // stage w1 chunk s (bf16 image copy from ws)
    {
      const uint4* src = (const uint4*)(wsbase + (size_t)s * CH);
      uint4* dst = (uint4*)sW;
      for (int i = tid; i < CH / 16; i += 256) dst[i] = src[i];
    }
    __syncthreads();
    #pragma unroll
    for (int kk = 0; kk < 64; kk += 32) {
      bf16x8 af[4], bfr[4];
      #pragma unroll
      for (int mt = 0; mt < 4; ++mt)
        af[mt] = *reinterpret_cast<const bf16x8*>(
            &sW[(wr * 64 + mt * 16 + l16) * 72 + kk + quad * 8]);
      #pragma unroll
      for (int nt = 0; nt < 4; ++nt)
        bfr[nt] = *reinterpret_cast<const bf16x8*>(
            &sH[(wc * 64 + nt * 16 + l16) * 72 + kk + quad * 8]);
      #pragma unroll
      for (int mt = 0; mt < 4; ++mt)
        #pragma unroll
        for (int nt = 0; nt < 4; ++nt)
          acc[mt][nt] = __builtin_amdgcn_mfma_f32_16x16x32_bf16(
              af[mt], bfr[nt], acc[mt][nt], 0, 0, 0);
    }
  }
  __syncthreads();

  // epilogue 1: relu(acc + b1) -> sH [batch][f], stride 136; + stage w2 c=0
  #pragma unroll
  for (int mt = 0; mt < 4; ++mt) {
    int fb = wr * 64 + mt * 16 + quad * 4;
    float4 bv = *reinterpret_cast<const float4*>(bias + fb);
    #pragma unroll
    for (int nt = 0; nt < 4; ++nt) {
      int bc = wc * 64 + nt * 16 + l16;
      f32x4 a = acc[mt][nt];
      ushort4 h;
      h.x = f2bf(fmaxf(a[0] + bv.x, 0.f));
      h.y = f2bf(fmaxf(a[1] + bv.y, 0.f));
      h.z = f2bf(fmaxf(a[2] + bv.z, 0.f));
      h.w = f2bf(fmaxf(a[3] + bv.w, 0.f));
      *reinterpret_cast<ushort4*>(&sH[bc * 136 + fb]) = h;
    }
  }
  {
    const uint4* src = (const uint4*)(wsbase + (size_t)n * CH);
    uint4* dst = (uint4*)sW;
    for (int i = tid; i < CH / 16; i += 256) dst[i] = src[i];
  }
  __syncthreads();

  // ---------------- layer 2: K = 128, 2 chunks -----------------------------
  #pragma unroll
  for (int a = 0; a < 4; ++a)
    #pragma unroll
    for (int b = 0; b < 4; ++b) acc[a][b] = (f32x4){0.f, 0.f, 0.f, 0.f};
  for (int c = 0; c < 2; ++c) {
    if (c) {
      __syncthreads();
      const uint4* src = (const uint4*)(wsbase + (size_t)(n + 1) * CH);
      uint4* dst = (uint4*)sW;
      for (int i = tid; i < CH / 16; i += 256) dst[i] = src[i];
      __syncthreads();
    }
    #pragma unroll
    for (int kk = 0; kk < 64; kk += 32) {
      bf16x8 af[4], bfr[4];
      #pragma unroll
      for (int mt = 0; mt < 4; ++mt)
        af[mt] = *reinterpret_cast<const bf16x8*>(
            &sW[(wr * 64 + mt * 16 + l16) * 72 + kk + quad * 8]);
      #pragma unroll
      for (int nt = 0; nt < 4; ++nt)
        bfr[nt] = *reinterpret_cast<const bf16x8*>(
            &sH[(wc * 64 + nt * 16 + l16) * 136 + c * 64 + kk + quad * 8]);
      #pragma unroll
      for (int mt = 0; mt < 4; ++mt)
        #pragma unroll
        for (int nt = 0; nt < 4; ++nt)
          acc[mt][nt] = __builtin_amdgcn_mfma_f32_16x16x32_bf16(
              af[mt], bfr[nt], acc[mt][nt], 0, 0, 0);
    }
  }
  __syncthreads();

  // epilogue 2: relu(acc + b2) -> sH; + stage w3 c=0
  #pragma unroll
  for (int mt = 0; mt < 4; ++mt) {
    int fb = wr * 64 + mt * 16 + quad * 4;
    float4 bv = *reinterpret_cast<const float4*>(bias + 128 + fb);
    #pragma unroll
    for (int nt = 0; nt < 4; ++nt) {
      int bc = wc * 64 + nt * 16 + l16;
      f32x4 a = acc[mt][nt];
      ushort4 h;
      h.x = f2bf(fmaxf(a[0] + bv.x, 0.f));
      h.y = f2bf(fmaxf(a[1] + bv.y, 0.f));
      h.z = f2bf(fmaxf(a[2] + bv.z, 0.f));
      h.w = f2bf(fmaxf(a[3] + bv.w, 0.f));
      *reinterpret_cast<ushort4*>(&sH[bc * 136 + fb]) = h;
    }
  }
  {
    const uint4* src = (const uint4*)(wsbase + (size_t)(n + 2) * CH);
    uint4* dst = (uint4*)sW;
    for (int i = tid; i < CH3 / 16; i += 256) dst[i] = src[i];
  }
  __syncthreads();

  // ---------------- layer 3: M = 64 feats, wave w owns 32 batch cols -------
  f32x4 acc3[4][2];
  #pragma unroll
  for (int a = 0; a < 4; ++a) { acc3[a][0] = (f32x4){0,0,0,0}; acc3[a][1] = (f32x4){0,0,0,0}; }
  for (int c = 0; c < 2; ++c) {
    if (c) {
      __syncthreads();
      const uint4* src = (const uint4*)(wsbase + (size_t)(n + 2) * CH + CH3);
      uint4* dst = (uint4*)sW;
      for (int i = tid; i < CH3 / 16; i += 256) dst[i] = src[i];
      __syncthreads();
    }
    #pragma unroll
    for (int kk = 0; kk < 64; kk += 32) {
      bf16x8 af[4], bfr[2];
      #pragma unroll
      for (int mt = 0; mt < 4; ++mt)
        af[mt] = *reinterpret_cast<const bf16x8*>(
            &sW[(mt * 16 + l16) * 72 + kk + quad * 8]);
      #pragma unroll
      for (int nt = 0; nt < 2; ++nt)
        bfr[nt] = *reinterpret_cast<const bf16x8*>(
            &sH[(w * 32 + nt * 16 + l16) * 136 + c * 64 + kk + quad * 8]);
      #pragma unroll
      for (int mt = 0; mt < 4; ++mt)
        #pragma unroll
        for (int nt = 0; nt < 2; ++nt)
          acc3[mt][nt] = __builtin_amdgcn_mfma_f32_16x16x32_bf16(
              af[mt], bfr[nt], acc3[mt][nt], 0, 0, 0);
    }
  }

  // epilogue 3: acc + b3 -> out[b, out_joint, :]
  const int oj = g_out[node];
  #pragma unroll
  for (int mt = 0; mt < 4; ++mt) {
    int fb = mt * 16 + quad * 4;
    float4 bv = *reinterpret_cast<const float4*>(bias + 256 + fb);
    #pragma unroll
    for (int nt = 0; nt < 2; ++nt) {
      int bc = w * 32 + nt * 16 + l16;
      f32x4 a = acc3[mt][nt];
      float4 o;
      o.x = a[0] + bv.x; o.y = a[1] + bv.y; o.z = a[2] + bv.z; o.w = a[3] + bv.w;
      *reinterpret_cast<float4*>(out + ((size_t)(b0 + bc) * 21 + oj) * 64 + fb) = o;
    }
  }
}

// ---------------- naive fp32 fallback (only if ws too small) ---------------
__global__ void mp_naive(const float* __restrict__ x, float* __restrict__ out,
                         WPtrs p) {
  const int node = blockIdx.x % 21;
  const int b0 = (blockIdx.x / 21) * 16;
  const int tid = threadIdx.x;
  const int n = g_n[node], gi = g_gi[node], ki = g_ki[node], oj = g_out[node];
  __shared__ float h1[16][128];
  __shared__ float h2[16][128];
  const float* w1 = p.w1[gi] + (size_t)ki * n * 64 * 128;
  const float* w2 = p.w2[gi] + (size_t)ki * 128 * 128;
  const float* w3 = p.w3[gi] + (size_t)ki * 128 * 64;
  for (int e = tid; e < 2048; e += 256) {
    int b = e >> 7, f = e & 127;
    float s = p.b1[gi][ki * 128 + f];
    for (int j = 0; j < n; ++j) {
      const float* xr = x + ((size_t)(b0 + b) * 21 + g_neigh[node][j]) * 64;
      const float* wr = w1 + (size_t)(j * 64) * 128 + f;
      for (int d = 0; d < 64; ++d) s += xr[d] * wr[(size_t)d * 128];
    }
    h1[b][f] = fmaxf(s, 0.f);
  }
  __syncthreads();
  for (int e = tid; e < 2048; e += 256) {
    int b = e >> 7, f = e & 127;
    float s = p.b2[gi][ki * 128 + f];
    for (int k = 0; k < 128; ++k) s += h1[b][k] * w2[(size_t)k * 128 + f];
    h2[b][f] = fmaxf(s, 0.f);
  }
  __syncthreads();
  for (int e = tid; e < 1024; e += 256) {
    int b = e >> 6, f = e & 63;
    float s = p.b3[gi][ki * 64 + f];
    for (int k = 0; k < 128; ++k) s += h2[b][k] * w3[(size_t)k * 64 + f];
    out[((size_t)(b0 + b) * 21 + oj) * 64 + f] = s;
  }
}

extern "C" void kernel_launch(void* const* d_in, const int* in_sizes, int n_in,
                              void* d_out, int out_size, void* d_ws, size_t ws_size,
                              hipStream_t stream) {
  const float* x = (const float*)d_in[0];
  float* out = (float*)d_out;
  WPtrs p;
  for (int g = 0; g < 5; ++g) {
    p.w1[g] = (const float*)d_in[1 + 6 * g];
    p.b1[g] = (const float*)d_in[2 + 6 * g];
    p.w2[g] = (const float*)d_in[3 + 6 * g];
    p.b2[g] = (const float*)d_in[4 + 6 * g];
    p.w3[g] = (const float*)d_in[5 + 6 * g];
    p.b3[g] = (const float*)d_in[6 + 6 * g];
  }
  const int B = in_sizes[0] / (21 * 64);
  if (ws_size >= WSNEED && (B % 128) == 0) {
    // 10 = max(n)+4 chunk slots: n w1-chunks, 2 w2-chunks, 2 w3-chunks (R2 fix)
    prep_weights<<<dim3(10, 21), 256, 0, stream>>>(p, (ushort*)d_ws);
    mp_mlp<<<dim3((B / 128) * 21), 256, 0, stream>>>(x, out, (const ushort*)d_ws);
  } else {
    mp_naive<<<dim3((B / 16) * 21), 256, 0, stream>>>(x, out, p);
  }
}